// Round 4
// baseline (673.731 us; speedup 1.0000x reference)
//
#include <hip/hip_runtime.h>
#include <hip/hip_fp16.h>
#include <math.h>

#define N_NODES 50000
#define MP      50048              /* padded rows = 782*64 */
#define N_EDGES 800000
#define E_TOT   (N_EDGES + N_NODES)
#define HEADS   4
#define CH      128
#define NOUT    512
#define NEG_SLOPE 0.2f

typedef unsigned int u32;
typedef __attribute__((ext_vector_type(8))) short bf16x8;
typedef __attribute__((ext_vector_type(4))) float f32x4;

__device__ __forceinline__ unsigned short f2bf(float f) {
  u32 u = __float_as_uint(f);
  u32 r = (u + 0x7FFFu + ((u >> 16) & 1u)) >> 16;   // RNE
  return (unsigned short)r;
}
__device__ __forceinline__ float bf2f(unsigned short h) {
  return __uint_as_float(((u32)h) << 16);
}

// ---------------- CSR build ----------------

__global__ __launch_bounds__(256) void count_deg(const int* __restrict__ ei,
                                                 int* __restrict__ deg) {
  int e = blockIdx.x * 256 + threadIdx.x;
  if (e >= E_TOT) return;
  int dst = (e < N_EDGES) ? ei[N_EDGES + e] : (e - N_EDGES);
  atomicAdd(&deg[dst], 1);
}

// single block, 1024 threads: per-thread sequential chunk + one 1024-wide scan
__global__ __launch_bounds__(1024) void scan_deg_fast(const int* __restrict__ deg,
                                                      int* __restrict__ row_ptr) {
  __shared__ int ssum[1024];
  const int tid = threadIdx.x;
  const int CHUNK = (N_NODES + 1023) / 1024;   // 49
  const int base = tid * CHUNK;
  int s = 0;
  for (int i = 0; i < CHUNK; ++i) {
    int idx = base + i;
    if (idx < N_NODES) s += deg[idx];
  }
  ssum[tid] = s;
  __syncthreads();
  for (int off = 1; off < 1024; off <<= 1) {
    int v = (tid >= off) ? ssum[tid - off] : 0;
    __syncthreads();
    ssum[tid] += v;
    __syncthreads();
  }
  int run = (tid > 0) ? ssum[tid - 1] : 0;
  for (int i = 0; i < CHUNK; ++i) {
    int idx = base + i;
    if (idx < N_NODES) { run += deg[idx]; row_ptr[idx + 1] = run; }
  }
  if (tid == 0) row_ptr[0] = 0;
}

__global__ __launch_bounds__(256) void scatter_edges(const int* __restrict__ ei,
                                                     const int* __restrict__ row_ptr,
                                                     int* __restrict__ cursor,
                                                     int* __restrict__ col) {
  int e = blockIdx.x * 256 + threadIdx.x;
  if (e >= E_TOT) return;
  int src, dst;
  if (e < N_EDGES) { src = ei[e]; dst = ei[N_EDGES + e]; }
  else             { src = e - N_EDGES; dst = src; }
  int pos = atomicAdd(&cursor[dst], 1);
  col[row_ptr[dst] + pos] = src;
}

// ---------------- weight split fp32 -> (bf16 hi, bf16 lo) ----------------

__global__ __launch_bounds__(256) void cvt_split_f32(const float* __restrict__ src,
                                                     unsigned short* __restrict__ hi,
                                                     unsigned short* __restrict__ lo,
                                                     int n4) {
  int i = blockIdx.x * 256 + threadIdx.x;
  if (i >= n4) return;
  float4 v = ((const float4*)src)[i];
  unsigned short h0 = f2bf(v.x), h1 = f2bf(v.y), h2 = f2bf(v.z), h3 = f2bf(v.w);
  ushort4 H = make_ushort4(h0, h1, h2, h3);
  ushort4 L = make_ushort4(f2bf(v.x - bf2f(h0)), f2bf(v.y - bf2f(h1)),
                           f2bf(v.z - bf2f(h2)), f2bf(v.w - bf2f(h3)));
  ((ushort4*)hi)[i] = H;
  ((ushort4*)lo)[i] = L;
}

// ---------------- fused split-bf16 GEMM + attention-scalar epilogue ----------------
// C_fp16[MP,512] = (A split)[M,K] @ (Bh+Bl)[512,K]^T  (3 MFMA products, fp32 acc)
// Block: 64 rows x 512 cols, 4 waves; wave w = head w (cols w*128..w*128+127).
// A staged ONCE into LDS (full K, split hi/lo, stride K+24 -> 2-way-only bank
// conflicts, 16B-aligned rows); K-loop is barrier-free; B read per-fragment
// from global (0.5 MB, L2-resident). Epilogue: fp16 C store + per-row
// as_/ad_ = <xh_row, att_{s,d}> via 16-lane shfl reduction (replaces node_att).

template <int K, typename SrcT>
__global__ __launch_bounds__(256, 2) void gemm_fused(
    const SrcT* __restrict__ A,
    const unsigned short* __restrict__ Bh, const unsigned short* __restrict__ Bl,
    const float* __restrict__ att_s, const float* __restrict__ att_d,
    __half* __restrict__ C, float* __restrict__ as_, float* __restrict__ ad_) {
  constexpr int LDK = K + 24;                 // stride: 16B-multiple rows, 2-way banks
  __shared__ unsigned short lA[2][64 * LDK];
  const int tid  = threadIdx.x;
  const int lane = tid & 63;
  const int wave = tid >> 6;                  // head
  const int m0   = blockIdx.x * 64;
  const int t    = lane & 15;
  const int quad = lane >> 4;
  const int kq   = quad * 8;

  // ---- stage & split A (once) ----
  {
    constexpr int QPR = K / 4;                // float4-quads per row
    for (int idx = tid; idx < 64 * QPR; idx += 256) {
      int row = idx / QPR, q = idx - row * QPR;
      float4 v;
      if (m0 + row < N_NODES) {
        if constexpr (sizeof(SrcT) == 4) {
          v = ((const float4*)((const float*)A + (size_t)(m0 + row) * K))[q];
        } else {
          uint2 p = ((const uint2*)((const __half*)A + (size_t)(m0 + row) * K))[q];
          __half2 h01 = *(__half2*)&p.x, h23 = *(__half2*)&p.y;
          float2 f01 = __half22float2(h01), f23 = __half22float2(h23);
          v = make_float4(f01.x, f01.y, f23.x, f23.y);
        }
      } else v = make_float4(0.f, 0.f, 0.f, 0.f);
      ushort4 H, L;
      H.x = f2bf(v.x); H.y = f2bf(v.y); H.z = f2bf(v.z); H.w = f2bf(v.w);
      L.x = f2bf(v.x - bf2f(H.x)); L.y = f2bf(v.y - bf2f(H.y));
      L.z = f2bf(v.z - bf2f(H.z)); L.w = f2bf(v.w - bf2f(H.w));
      *(ushort4*)&lA[0][row * LDK + q * 4] = H;
      *(ushort4*)&lA[1][row * LDK + q * 4] = L;
    }
  }
  __syncthreads();

  f32x4 acc[4][8];
#pragma unroll
  for (int i = 0; i < 4; i++)
#pragma unroll
    for (int j = 0; j < 8; j++) acc[i][j] = (f32x4){0.f, 0.f, 0.f, 0.f};

  const int nbase = wave * 128 + t;

  for (int k0 = 0; k0 < K; k0 += 32) {
    bf16x8 a[4][2];
#pragma unroll
    for (int i = 0; i < 4; ++i) {
      a[i][0] = *(const bf16x8*)&lA[0][(i * 16 + t) * LDK + k0 + kq];
      a[i][1] = *(const bf16x8*)&lA[1][(i * 16 + t) * LDK + k0 + kq];
    }
#pragma unroll
    for (int jh = 0; jh < 2; ++jh) {
      bf16x8 b[4][2];
#pragma unroll
      for (int jj = 0; jj < 4; ++jj) {
        int j = jh * 4 + jj;
        size_t boff = (size_t)(nbase + j * 16) * K + k0 + kq;
        b[jj][0] = *(const bf16x8*)(Bh + boff);
        b[jj][1] = *(const bf16x8*)(Bl + boff);
      }
#pragma unroll
      for (int i = 0; i < 4; ++i)
#pragma unroll
        for (int jj = 0; jj < 4; ++jj) {
          int j = jh * 4 + jj;
          acc[i][j] = __builtin_amdgcn_mfma_f32_16x16x32_bf16(a[i][0], b[jj][0], acc[i][j], 0, 0, 0);
          acc[i][j] = __builtin_amdgcn_mfma_f32_16x16x32_bf16(a[i][0], b[jj][1], acc[i][j], 0, 0, 0);
          acc[i][j] = __builtin_amdgcn_mfma_f32_16x16x32_bf16(a[i][1], b[jj][0], acc[i][j], 0, 0, 0);
        }
    }
  }

  // ---- epilogue: C fp16 store + as_/ad_ reduction ----
  const float* asv = att_s + wave * CH;
  const float* adv = att_d + wave * CH;
#pragma unroll
  for (int i = 0; i < 4; ++i) {
    float s_as[4] = {0.f, 0.f, 0.f, 0.f};
    float s_ad[4] = {0.f, 0.f, 0.f, 0.f};
#pragma unroll
    for (int j = 0; j < 8; ++j) {
      int c = j * 16 + t;
      float sc = asv[c], dc = adv[c];
#pragma unroll
      for (int r = 0; r < 4; ++r) {
        float xv = acc[i][j][r];
        s_as[r] = fmaf(xv, sc, s_as[r]);
        s_ad[r] = fmaf(xv, dc, s_ad[r]);
        int row = m0 + i * 16 + quad * 4 + r;
        C[(size_t)row * NOUT + wave * 128 + c] = __float2half(xv);
      }
    }
#pragma unroll
    for (int r = 0; r < 4; ++r) {
#pragma unroll
      for (int mask = 1; mask < 16; mask <<= 1) {
        s_as[r] += __shfl_xor(s_as[r], mask, 64);
        s_ad[r] += __shfl_xor(s_ad[r], mask, 64);
      }
      if (t == 0) {
        int row = m0 + i * 16 + quad * 4 + r;
        if (row < N_NODES) {
          as_[row * HEADS + wave] = s_as[r];
          ad_[row * HEADS + wave] = s_ad[r];
        }
      }
    }
  }
}

// ---------------- GAT aggregation, fp16 gather ----------------
// one wave per dst node. lane -> (h, 8 channels) => one 16 B load per edge.
// No explicit segment-max (|alpha|max ~ 8 << 88, algebraically identical).

template <bool HALF_OUT>
__global__ __launch_bounds__(256) void gat_aggregate_f16(const __half* __restrict__ xh,
                                                         const float* __restrict__ as_,
                                                         const float* __restrict__ ad_,
                                                         const int* __restrict__ row_ptr,
                                                         const int* __restrict__ col,
                                                         const float* __restrict__ bias,
                                                         void* __restrict__ outv) {
  int node = (blockIdx.x * 256 + threadIdx.x) >> 6;
  if (node >= N_NODES) return;
  int lane = threadIdx.x & 63;
  int h = lane >> 4, ls = lane & 15, cb = ls * 8;
  int s = row_ptr[node], e = row_ptr[node + 1];
  float adh = ad_[node * HEADS + h];

  float acc[8];
#pragma unroll
  for (int j = 0; j < 8; j++) acc[j] = 0.f;
  float denom = 0.f;

  auto accum = [&](uint4 q, float w) {
    __half2 q0 = *(__half2*)&q.x, q1 = *(__half2*)&q.y;
    __half2 q2 = *(__half2*)&q.z, q3 = *(__half2*)&q.w;
    float2 f0 = __half22float2(q0), f1 = __half22float2(q1);
    float2 f2 = __half22float2(q2), f3 = __half22float2(q3);
    acc[0] = fmaf(w, f0.x, acc[0]); acc[1] = fmaf(w, f0.y, acc[1]);
    acc[2] = fmaf(w, f1.x, acc[2]); acc[3] = fmaf(w, f1.y, acc[3]);
    acc[4] = fmaf(w, f2.x, acc[4]); acc[5] = fmaf(w, f2.y, acc[5]);
    acc[6] = fmaf(w, f3.x, acc[6]); acc[7] = fmaf(w, f3.y, acc[7]);
  };

  int i = s;
  for (; i + 4 <= e; i += 4) {
    int s0 = col[i], s1 = col[i + 1], s2 = col[i + 2], s3 = col[i + 3];
    float l0 = as_[s0 * HEADS + h];
    float l1 = as_[s1 * HEADS + h];
    float l2 = as_[s2 * HEADS + h];
    float l3 = as_[s3 * HEADS + h];
    uint4 q0 = *(const uint4*)(xh + (size_t)s0 * NOUT + h * CH + cb);
    uint4 q1 = *(const uint4*)(xh + (size_t)s1 * NOUT + h * CH + cb);
    uint4 q2 = *(const uint4*)(xh + (size_t)s2 * NOUT + h * CH + cb);
    uint4 q3 = *(const uint4*)(xh + (size_t)s3 * NOUT + h * CH + cb);
    float a0 = l0 + adh; a0 = (a0 >= 0.f) ? a0 : NEG_SLOPE * a0;
    float a1 = l1 + adh; a1 = (a1 >= 0.f) ? a1 : NEG_SLOPE * a1;
    float a2 = l2 + adh; a2 = (a2 >= 0.f) ? a2 : NEG_SLOPE * a2;
    float a3 = l3 + adh; a3 = (a3 >= 0.f) ? a3 : NEG_SLOPE * a3;
    float w0 = __expf(a0), w1 = __expf(a1), w2 = __expf(a2), w3 = __expf(a3);
    denom += (w0 + w1) + (w2 + w3);
    accum(q0, w0); accum(q1, w1); accum(q2, w2); accum(q3, w3);
  }
  for (; i < e; ++i) {
    int src = col[i];
    float l = as_[src * HEADS + h];
    uint4 q = *(const uint4*)(xh + (size_t)src * NOUT + h * CH + cb);
    float a = l + adh; a = (a >= 0.f) ? a : NEG_SLOPE * a;
    float w = __expf(a);
    denom += w;
    accum(q, w);
  }

  float inv = 1.f / (denom + 1e-16f);
#pragma unroll
  for (int j = 0; j < 8; j++) acc[j] *= inv;

  // mean over heads: butterfly over lane bits 4,5
#pragma unroll
  for (int j = 0; j < 8; j++) {
    acc[j] += __shfl_xor(acc[j], 16, 64);
    acc[j] += __shfl_xor(acc[j], 32, 64);
  }
  if (h == 0) {
    float r[8];
#pragma unroll
    for (int j = 0; j < 8; j++) r[j] = acc[j] * 0.25f + bias[cb + j];
    if (HALF_OUT) {
      __half2 o[4];
#pragma unroll
      for (int j = 0; j < 4; j++)
        o[j] = __float22half2_rn(make_float2(r[2 * j], r[2 * j + 1]));
      *(uint4*)((__half*)outv + (size_t)node * CH + cb) = *(uint4*)o;
    } else {
      float4 o0 = make_float4(r[0], r[1], r[2], r[3]);
      float4 o1 = make_float4(r[4], r[5], r[6], r[7]);
      *(float4*)((float*)outv + (size_t)node * CH + cb)     = o0;
      *(float4*)((float*)outv + (size_t)node * CH + cb + 4) = o1;
    }
  }
}

// ---------------- launch ----------------

extern "C" void kernel_launch(void* const* d_in, const int* in_sizes, int n_in,
                              void* d_out, int out_size, void* d_ws, size_t ws_size,
                              hipStream_t stream) {
  const float* x      = (const float*)d_in[0];
  const int*   ei     = (const int*)  d_in[1];
  const float* W1     = (const float*)d_in[2];
  const float* att_s1 = (const float*)d_in[3];
  const float* att_d1 = (const float*)d_in[4];
  const float* b1     = (const float*)d_in[5];
  const float* W2     = (const float*)d_in[6];
  const float* att_s2 = (const float*)d_in[7];
  const float* att_d2 = (const float*)d_in[8];
  const float* b2     = (const float*)d_in[9];
  float* out = (float*)d_out;

  char* ws = (char*)d_ws;
  size_t off = 0;
  auto alloc = [&](size_t bytes) -> void* {
    void* p = ws + off;
    off += (bytes + 255) & ~(size_t)255;
    return p;
  };
  unsigned short* Wh1  = (unsigned short*)alloc((size_t)512 * 256 * 2);
  unsigned short* Wl1  = (unsigned short*)alloc((size_t)512 * 256 * 2);
  unsigned short* Wh2  = (unsigned short*)alloc((size_t)512 * 128 * 2);
  unsigned short* Wl2  = (unsigned short*)alloc((size_t)512 * 128 * 2);
  __half* xh16   = (__half*)alloc((size_t)MP * NOUT * 2);               // 51.2 MB
  __half* hbuf16 = (__half*)alloc((size_t)N_NODES * CH * 2);            // 12.8 MB
  float* as_     = (float*)alloc((size_t)N_NODES * HEADS * 4);
  float* ad_     = (float*)alloc((size_t)N_NODES * HEADS * 4);
  int*   row_ptr = (int*)alloc((size_t)(N_NODES + 1) * 4);
  int*   cursor  = (int*)alloc((size_t)N_NODES * 4);
  int*   col     = (int*)alloc((size_t)E_TOT * 4);

  const int edge_blocks = (E_TOT + 255) / 256;
  const int node_wave_blocks = (N_NODES + 3) / 4;
  const int gemm_blocks = MP / 64;   // 782

  // CSR build (by dst)
  hipMemsetAsync(cursor, 0, (size_t)N_NODES * 4, stream);
  count_deg<<<edge_blocks, 256, 0, stream>>>(ei, cursor);
  scan_deg_fast<<<1, 1024, 0, stream>>>(cursor, row_ptr);
  hipMemsetAsync(cursor, 0, (size_t)N_NODES * 4, stream);
  scatter_edges<<<edge_blocks, 256, 0, stream>>>(ei, row_ptr, cursor, col);

  // weight splits
  cvt_split_f32<<<(512 * 256 / 4 + 255) / 256, 256, 0, stream>>>(W1, Wh1, Wl1, 512 * 256 / 4);
  cvt_split_f32<<<(512 * 128 / 4 + 255) / 256, 256, 0, stream>>>(W2, Wh2, Wl2, 512 * 128 / 4);

  // layer 1
  gemm_fused<256, float><<<gemm_blocks, 256, 0, stream>>>(
      x, Wh1, Wl1, att_s1, att_d1, xh16, as_, ad_);
  gat_aggregate_f16<true><<<node_wave_blocks, 256, 0, stream>>>(
      xh16, as_, ad_, row_ptr, col, b1, hbuf16);

  // layer 2
  gemm_fused<128, __half><<<gemm_blocks, 256, 0, stream>>>(
      hbuf16, Wh2, Wl2, att_s2, att_d2, xh16, as_, ad_);
  gat_aggregate_f16<false><<<node_wave_blocks, 256, 0, stream>>>(
      xh16, as_, ad_, row_ptr, col, b2, out);
}

// Round 5
// 658.406 us; speedup vs baseline: 1.0233x; 1.0233x over previous
//
#include <hip/hip_runtime.h>
#include <hip/hip_fp16.h>
#include <math.h>

#define N_NODES 50000
#define MP      50048              /* padded rows = 391*128 */
#define N_EDGES 800000
#define E_TOT   (N_EDGES + N_NODES)
#define HEADS   4
#define CH      128
#define NOUT    512
#define NEG_SLOPE 0.2f

typedef unsigned int u32;
typedef unsigned short u16;
typedef __attribute__((ext_vector_type(8))) short bf16x8;
typedef __attribute__((ext_vector_type(4))) float f32x4;

__device__ __forceinline__ u16 f2bf(float f) {
  u32 u = __float_as_uint(f);
  u32 r = (u + 0x7FFFu + ((u >> 16) & 1u)) >> 16;   // RNE
  return (u16)r;
}
__device__ __forceinline__ float bf2f(u16 h) {
  return __uint_as_float(((u32)h) << 16);
}

// ---------------- CSR build ----------------

__global__ __launch_bounds__(256) void count_deg(const int* __restrict__ ei,
                                                 int* __restrict__ deg) {
  int e = blockIdx.x * 256 + threadIdx.x;
  if (e >= E_TOT) return;
  int dst = (e < N_EDGES) ? ei[N_EDGES + e] : (e - N_EDGES);
  atomicAdd(&deg[dst], 1);
}

// single block, 1024 threads: per-thread sequential chunk + one 1024-wide scan
__global__ __launch_bounds__(1024) void scan_deg_fast(const int* __restrict__ deg,
                                                      int* __restrict__ row_ptr) {
  __shared__ int ssum[1024];
  const int tid = threadIdx.x;
  const int CHUNK = (N_NODES + 1023) / 1024;   // 49
  const int base = tid * CHUNK;
  int s = 0;
  for (int i = 0; i < CHUNK; ++i) {
    int idx = base + i;
    if (idx < N_NODES) s += deg[idx];
  }
  ssum[tid] = s;
  __syncthreads();
  for (int off = 1; off < 1024; off <<= 1) {
    int v = (tid >= off) ? ssum[tid - off] : 0;
    __syncthreads();
    ssum[tid] += v;
    __syncthreads();
  }
  int run = (tid > 0) ? ssum[tid - 1] : 0;
  for (int i = 0; i < CHUNK; ++i) {
    int idx = base + i;
    if (idx < N_NODES) { run += deg[idx]; row_ptr[idx + 1] = run; }
  }
  if (tid == 0) row_ptr[0] = 0;
}

__global__ __launch_bounds__(256) void scatter_edges(const int* __restrict__ ei,
                                                     const int* __restrict__ row_ptr,
                                                     int* __restrict__ cursor,
                                                     int* __restrict__ col) {
  int e = blockIdx.x * 256 + threadIdx.x;
  if (e >= E_TOT) return;
  int src, dst;
  if (e < N_EDGES) { src = ei[e]; dst = ei[N_EDGES + e]; }
  else             { src = e - N_EDGES; dst = src; }
  int pos = atomicAdd(&cursor[dst], 1);
  col[row_ptr[dst] + pos] = src;
}

// ---------------- combined split: x, W1, W2 -> (bf16 hi, bf16 lo) ----------------

#define CVT_N0 (N_NODES * 256 / 4)        /* 3,200,000 float4 for x  */
#define CVT_N1 (CVT_N0 + 512 * 256 / 4)   /* + 32768 for W1 */
#define CVT_N2 (CVT_N1 + 512 * 128 / 4)   /* + 16384 for W2 */

__global__ __launch_bounds__(256) void cvt_all(
    const float* __restrict__ x,  u16* __restrict__ Ah,  u16* __restrict__ Al,
    const float* __restrict__ W1, u16* __restrict__ Wh1, u16* __restrict__ Wl1,
    const float* __restrict__ W2, u16* __restrict__ Wh2, u16* __restrict__ Wl2) {
  int i = blockIdx.x * 256 + threadIdx.x;
  const float* s; u16* ph; u16* pl; int k;
  if (i < CVT_N0)      { s = x;  ph = Ah;  pl = Al;  k = i; }
  else if (i < CVT_N1) { s = W1; ph = Wh1; pl = Wl1; k = i - CVT_N0; }
  else if (i < CVT_N2) { s = W2; ph = Wh2; pl = Wl2; k = i - CVT_N1; }
  else return;
  float4 v = ((const float4*)s)[k];
  ushort4 H, L;
  H.x = f2bf(v.x); H.y = f2bf(v.y); H.z = f2bf(v.z); H.w = f2bf(v.w);
  L.x = f2bf(v.x - bf2f(H.x)); L.y = f2bf(v.y - bf2f(H.y));
  L.z = f2bf(v.z - bf2f(H.z)); L.w = f2bf(v.w - bf2f(H.w));
  ((ushort4*)ph)[k] = H;
  ((ushort4*)pl)[k] = L;
}

// ---------------- split-bf16 MFMA GEMM + fused attention epilogue ----------------
// C_fp16[MP,512] = (Ah+Al)[M,K] @ (Bh+Bl)[512,K]^T   (3 products, fp32 acc)
// Grid (MP/128, 4): block = 128 rows x 128 cols; col-block == head hb.
// Staging: round-3 pattern, global_load_lds width=16, 32 KB LDS, 2 barriers/K-step.
// Epilogue: (1) per-row <xh,att_s/d> via 16-lane shfl + LDS combine across the
// two col-waves (replaces node_att); (2) C stored fp16 via LDS repack ->
// 8 full-line dwordx4 stores per lane (replaces 64 scalar 2B stores).

#define GLD16(gp, lp)                                                          \
  __builtin_amdgcn_global_load_lds(                                            \
      (const __attribute__((address_space(1))) u32*)(gp),                      \
      (__attribute__((address_space(3))) u32*)(lp), 16, 0, 0)

template <int K>
__global__ __launch_bounds__(256) void gemm_att(
    const u16* __restrict__ Ah, const u16* __restrict__ Al,
    const u16* __restrict__ Bh, const u16* __restrict__ Bl,
    const float* __restrict__ att_s, const float* __restrict__ att_d,
    __half* __restrict__ C, float* __restrict__ as_, float* __restrict__ ad_) {
  __shared__ char smem_raw[36864];           // 32 KB staging; 34.8 KB as sC alias
  __shared__ float sAtt[2][4][64];
  u16* lds = (u16*)smem_raw;                 // planes: Ah,Al,Bh,Bl @ 4096 u16 each
  const int tid  = threadIdx.x;
  const int lane = tid & 63;
  const int wave = tid >> 6;
  const int m0 = blockIdx.x * 128;
  const int hb = blockIdx.y;
  const int n0 = hb * 128;
  const int wm = (wave >> 1) * 64, wn = (wave & 1) * 64;
  const int t = lane & 15, quad = lane >> 4, kq = quad * 8;

  f32x4 acc[4][4];
#pragma unroll
  for (int i = 0; i < 4; i++)
#pragma unroll
    for (int j = 0; j < 4; j++) acc[i][j] = (f32x4){0.f, 0.f, 0.f, 0.f};

  const int srow = tid >> 2;            // staging row (0..63), 2 r-iters
  const int skc  = (tid & 3) * 8;       // staging k offset (elements)

  for (int k0 = 0; k0 < K; k0 += 32) {
    __syncthreads();
#pragma unroll
    for (int r = 0; r < 2; ++r) {
      int row = r * 64 + srow;
      size_t aoff = (size_t)(m0 + row) * K + k0 + skc;
      size_t boff = (size_t)(n0 + row) * K + k0 + skc;
      int ld = r * 4096 + tid * 16;     // byte offset within an 8 KB plane
      GLD16(Ah + aoff, (char*)lds + ld);
      GLD16(Al + aoff, (char*)lds + 8192 + ld);
      GLD16(Bh + boff, (char*)lds + 16384 + ld);
      GLD16(Bl + boff, (char*)lds + 24576 + ld);
    }
    __syncthreads();

    bf16x8 a[4][2], b[4][2];
#pragma unroll
    for (int i = 0; i < 4; ++i) {
      a[i][0] = *(const bf16x8*)&lds[0 * 4096 + (wm + t + i * 16) * 32 + kq];
      a[i][1] = *(const bf16x8*)&lds[1 * 4096 + (wm + t + i * 16) * 32 + kq];
      b[i][0] = *(const bf16x8*)&lds[2 * 4096 + (wn + t + i * 16) * 32 + kq];
      b[i][1] = *(const bf16x8*)&lds[3 * 4096 + (wn + t + i * 16) * 32 + kq];
    }
#pragma unroll
    for (int i = 0; i < 4; ++i)
#pragma unroll
      for (int j = 0; j < 4; ++j) {
        acc[i][j] = __builtin_amdgcn_mfma_f32_16x16x32_bf16(a[i][0], b[j][0], acc[i][j], 0, 0, 0);
        acc[i][j] = __builtin_amdgcn_mfma_f32_16x16x32_bf16(a[i][0], b[j][1], acc[i][j], 0, 0, 0);
        acc[i][j] = __builtin_amdgcn_mfma_f32_16x16x32_bf16(a[i][1], b[j][0], acc[i][j], 0, 0, 0);
      }
  }

  // ---- att partials (regs only; write to sAtt before the barrier) ----
  const float* asv = att_s + hb * CH;
  const float* adv = att_d + hb * CH;
#pragma unroll
  for (int i = 0; i < 4; ++i) {
    float sa[4] = {0.f, 0.f, 0.f, 0.f}, sd[4] = {0.f, 0.f, 0.f, 0.f};
#pragma unroll
    for (int j = 0; j < 4; ++j) {
      int c = wn + j * 16 + t;
      float sc = asv[c], dc = adv[c];
#pragma unroll
      for (int r = 0; r < 4; ++r) {
        sa[r] = fmaf(acc[i][j][r], sc, sa[r]);
        sd[r] = fmaf(acc[i][j][r], dc, sd[r]);
      }
    }
#pragma unroll
    for (int r = 0; r < 4; ++r) {
#pragma unroll
      for (int mask = 1; mask < 16; mask <<= 1) {
        sa[r] += __shfl_xor(sa[r], mask, 64);
        sd[r] += __shfl_xor(sd[r], mask, 64);
      }
      if (t == 0) {
        sAtt[0][wave][i * 16 + quad * 4 + r] = sa[r];
        sAtt[1][wave][i * 16 + quad * 4 + r] = sd[r];
      }
    }
  }
  __syncthreads();   // staging reads + sAtt writes complete; safe to alias lds

  // ---- C repack through LDS (alias): [256][68] halves = 34816 B ----
  __half (*sC)[68] = (__half(*)[68])smem_raw;
#pragma unroll
  for (int i = 0; i < 4; ++i)
#pragma unroll
    for (int j = 0; j < 4; ++j)
#pragma unroll
      for (int r = 0; r < 4; ++r)
        sC[wave * 64 + i * 16 + quad * 4 + r][j * 16 + t] = __float2half(acc[i][j][r]);
  __syncthreads();

  {
    const int r8 = lane >> 3, q = lane & 7;
#pragma unroll
    for (int g = 0; g < 8; ++g) {
      int row = r8 + g * 8;                  // 0..63 within wave tile
      uint4 v = *(const uint4*)&sC[wave * 64 + row][q * 8];
      int gm = m0 + wm + row;
      *(uint4*)&C[(size_t)gm * NOUT + n0 + wn + q * 8] = v;
    }
  }

  // ---- att finals: combine the two col-waves of each row-half ----
  if ((wave & 1) == 0) {
    int rl = lane;                           // 0..63
    int gm = m0 + (wave >> 1) * 64 + rl;
    if (gm < N_NODES) {
      as_[gm * HEADS + hb] = sAtt[0][wave][rl] + sAtt[0][wave + 1][rl];
      ad_[gm * HEADS + hb] = sAtt[1][wave][rl] + sAtt[1][wave + 1][rl];
    }
  }
}

// ---------------- GAT aggregation, fp16 gather ----------------
// one wave per dst node. lane -> (h, 8 channels) => one 16 B load per edge.
// No explicit segment-max (|alpha|max ~ 8 << 88, algebraically identical).
// MODE 0: write split-bf16 (hi/lo) — feeds layer-2 GEMM directly (no cvt pass).
// MODE 1: write fp32 to final output.

template <int MODE>
__global__ __launch_bounds__(256) void gat_aggregate_f16(const __half* __restrict__ xh,
                                                         const float* __restrict__ as_,
                                                         const float* __restrict__ ad_,
                                                         const int* __restrict__ row_ptr,
                                                         const int* __restrict__ col,
                                                         const float* __restrict__ bias,
                                                         u16* __restrict__ oh,
                                                         u16* __restrict__ ol,
                                                         float* __restrict__ outf) {
  int node = (blockIdx.x * 256 + threadIdx.x) >> 6;
  if (node >= N_NODES) return;
  int lane = threadIdx.x & 63;
  int h = lane >> 4, ls = lane & 15, cb = ls * 8;
  int s = row_ptr[node], e = row_ptr[node + 1];
  float adh = ad_[node * HEADS + h];

  float acc[8];
#pragma unroll
  for (int j = 0; j < 8; j++) acc[j] = 0.f;
  float denom = 0.f;

  auto accum = [&](uint4 q, float w) {
    __half2 q0 = *(__half2*)&q.x, q1 = *(__half2*)&q.y;
    __half2 q2 = *(__half2*)&q.z, q3 = *(__half2*)&q.w;
    float2 f0 = __half22float2(q0), f1 = __half22float2(q1);
    float2 f2 = __half22float2(q2), f3 = __half22float2(q3);
    acc[0] = fmaf(w, f0.x, acc[0]); acc[1] = fmaf(w, f0.y, acc[1]);
    acc[2] = fmaf(w, f1.x, acc[2]); acc[3] = fmaf(w, f1.y, acc[3]);
    acc[4] = fmaf(w, f2.x, acc[4]); acc[5] = fmaf(w, f2.y, acc[5]);
    acc[6] = fmaf(w, f3.x, acc[6]); acc[7] = fmaf(w, f3.y, acc[7]);
  };

  int i = s;
  for (; i + 4 <= e; i += 4) {
    int s0 = col[i], s1 = col[i + 1], s2 = col[i + 2], s3 = col[i + 3];
    float l0 = as_[s0 * HEADS + h];
    float l1 = as_[s1 * HEADS + h];
    float l2 = as_[s2 * HEADS + h];
    float l3 = as_[s3 * HEADS + h];
    uint4 q0 = *(const uint4*)(xh + (size_t)s0 * NOUT + h * CH + cb);
    uint4 q1 = *(const uint4*)(xh + (size_t)s1 * NOUT + h * CH + cb);
    uint4 q2 = *(const uint4*)(xh + (size_t)s2 * NOUT + h * CH + cb);
    uint4 q3 = *(const uint4*)(xh + (size_t)s3 * NOUT + h * CH + cb);
    float a0 = l0 + adh; a0 = (a0 >= 0.f) ? a0 : NEG_SLOPE * a0;
    float a1 = l1 + adh; a1 = (a1 >= 0.f) ? a1 : NEG_SLOPE * a1;
    float a2 = l2 + adh; a2 = (a2 >= 0.f) ? a2 : NEG_SLOPE * a2;
    float a3 = l3 + adh; a3 = (a3 >= 0.f) ? a3 : NEG_SLOPE * a3;
    float w0 = __expf(a0), w1 = __expf(a1), w2 = __expf(a2), w3 = __expf(a3);
    denom += (w0 + w1) + (w2 + w3);
    accum(q0, w0); accum(q1, w1); accum(q2, w2); accum(q3, w3);
  }
  for (; i < e; ++i) {
    int src = col[i];
    float l = as_[src * HEADS + h];
    uint4 q = *(const uint4*)(xh + (size_t)src * NOUT + h * CH + cb);
    float a = l + adh; a = (a >= 0.f) ? a : NEG_SLOPE * a;
    float w = __expf(a);
    denom += w;
    accum(q, w);
  }

  float inv = 1.f / (denom + 1e-16f);
#pragma unroll
  for (int j = 0; j < 8; j++) acc[j] *= inv;

  // mean over heads: butterfly over lane bits 4,5
#pragma unroll
  for (int j = 0; j < 8; j++) {
    acc[j] += __shfl_xor(acc[j], 16, 64);
    acc[j] += __shfl_xor(acc[j], 32, 64);
  }
  if (h == 0) {
    float r[8];
#pragma unroll
    for (int j = 0; j < 8; j++) r[j] = acc[j] * 0.25f + bias[cb + j];
    if (MODE == 0) {
      u16 H[8], L[8];
#pragma unroll
      for (int j = 0; j < 8; j++) {
        H[j] = f2bf(r[j]);
        L[j] = f2bf(r[j] - bf2f(H[j]));
      }
      *(uint4*)&oh[(size_t)node * CH + cb] = *(uint4*)H;
      *(uint4*)&ol[(size_t)node * CH + cb] = *(uint4*)L;
    } else {
      float4 o0 = make_float4(r[0], r[1], r[2], r[3]);
      float4 o1 = make_float4(r[4], r[5], r[6], r[7]);
      *(float4*)&outf[(size_t)node * CH + cb]     = o0;
      *(float4*)&outf[(size_t)node * CH + cb + 4] = o1;
    }
  }
}

// ---------------- launch ----------------

extern "C" void kernel_launch(void* const* d_in, const int* in_sizes, int n_in,
                              void* d_out, int out_size, void* d_ws, size_t ws_size,
                              hipStream_t stream) {
  const float* x      = (const float*)d_in[0];
  const int*   ei     = (const int*)  d_in[1];
  const float* W1     = (const float*)d_in[2];
  const float* att_s1 = (const float*)d_in[3];
  const float* att_d1 = (const float*)d_in[4];
  const float* b1     = (const float*)d_in[5];
  const float* W2     = (const float*)d_in[6];
  const float* att_s2 = (const float*)d_in[7];
  const float* att_d2 = (const float*)d_in[8];
  const float* b2     = (const float*)d_in[9];
  float* out = (float*)d_out;

  char* ws = (char*)d_ws;
  size_t off = 0;
  auto alloc = [&](size_t bytes) -> void* {
    void* p = ws + off;
    off += (bytes + 255) & ~(size_t)255;
    return p;
  };
  u16* Ah  = (u16*)alloc((size_t)MP * 256 * 2);   // layer1 A-split; layer2 reuses (stride 128)
  u16* Al  = (u16*)alloc((size_t)MP * 256 * 2);
  u16* Wh1 = (u16*)alloc((size_t)512 * 256 * 2);
  u16* Wl1 = (u16*)alloc((size_t)512 * 256 * 2);
  u16* Wh2 = (u16*)alloc((size_t)512 * 128 * 2);
  u16* Wl2 = (u16*)alloc((size_t)512 * 128 * 2);
  __half* xh16 = (__half*)alloc((size_t)MP * NOUT * 2);    // 51.2 MB
  float* as_     = (float*)alloc((size_t)N_NODES * HEADS * 4);
  float* ad_     = (float*)alloc((size_t)N_NODES * HEADS * 4);
  int*   row_ptr = (int*)alloc((size_t)(N_NODES + 1) * 4);
  int*   cursor  = (int*)alloc((size_t)N_NODES * 4);
  int*   col     = (int*)alloc((size_t)E_TOT * 4);

  const int edge_blocks = (E_TOT + 255) / 256;
  const int node_wave_blocks = (N_NODES + 3) / 4;
  dim3 ggrid(MP / 128, HEADS);   // 391 x 4

  // CSR build (by dst)
  hipMemsetAsync(cursor, 0, (size_t)N_NODES * 4, stream);
  count_deg<<<edge_blocks, 256, 0, stream>>>(ei, cursor);
  scan_deg_fast<<<1, 1024, 0, stream>>>(cursor, row_ptr);
  hipMemsetAsync(cursor, 0, (size_t)N_NODES * 4, stream);
  scatter_edges<<<edge_blocks, 256, 0, stream>>>(ei, row_ptr, cursor, col);

  // split x, W1, W2 in one pass
  cvt_all<<<(CVT_N2 + 255) / 256, 256, 0, stream>>>(x, Ah, Al, W1, Wh1, Wl1, W2, Wh2, Wl2);

  // layer 1
  gemm_att<256><<<ggrid, 256, 0, stream>>>(Ah, Al, Wh1, Wl1, att_s1, att_d1,
                                           xh16, as_, ad_);
  gat_aggregate_f16<0><<<node_wave_blocks, 256, 0, stream>>>(
      xh16, as_, ad_, row_ptr, col, b1, Ah, Al, nullptr);

  // layer 2 (A = split written by aggregate-1, stride 128)
  gemm_att<128><<<ggrid, 256, 0, stream>>>(Ah, Al, Wh2, Wl2, att_s2, att_d2,
                                           xh16, as_, ad_);
  gat_aggregate_f16<1><<<node_wave_blocks, 256, 0, stream>>>(
      xh16, as_, ad_, row_ptr, col, b2, nullptr, nullptr, out);
}

// Round 6
// 614.615 us; speedup vs baseline: 1.0962x; 1.0712x over previous
//
#include <hip/hip_runtime.h>
#include <hip/hip_fp16.h>
#include <math.h>

#define N_NODES 50000
#define MP      50048              /* padded rows = 391*128 */
#define N_EDGES 800000
#define E_TOT   (N_EDGES + N_NODES)
#define HEADS   4
#define CH      128
#define NOUT    512
#define NEG_SLOPE 0.2f

typedef unsigned int u32;
typedef unsigned short u16;
typedef __attribute__((ext_vector_type(8))) _Float16 f16x8;
typedef __attribute__((ext_vector_type(4))) float f32x4;

// ---------------- CSR build ----------------

__global__ __launch_bounds__(256) void count_deg(const int* __restrict__ ei,
                                                 int* __restrict__ deg) {
  int e = blockIdx.x * 256 + threadIdx.x;
  if (e >= E_TOT) return;
  int dst = (e < N_EDGES) ? ei[N_EDGES + e] : (e - N_EDGES);
  atomicAdd(&deg[dst], 1);
}

// single block, 1024 threads: per-thread sequential chunk + one 1024-wide scan
__global__ __launch_bounds__(1024) void scan_deg_fast(const int* __restrict__ deg,
                                                      int* __restrict__ row_ptr) {
  __shared__ int ssum[1024];
  const int tid = threadIdx.x;
  const int CHUNK = (N_NODES + 1023) / 1024;   // 49
  const int base = tid * CHUNK;
  int s = 0;
  for (int i = 0; i < CHUNK; ++i) {
    int idx = base + i;
    if (idx < N_NODES) s += deg[idx];
  }
  ssum[tid] = s;
  __syncthreads();
  for (int off = 1; off < 1024; off <<= 1) {
    int v = (tid >= off) ? ssum[tid - off] : 0;
    __syncthreads();
    ssum[tid] += v;
    __syncthreads();
  }
  int run = (tid > 0) ? ssum[tid - 1] : 0;
  for (int i = 0; i < CHUNK; ++i) {
    int idx = base + i;
    if (idx < N_NODES) { run += deg[idx]; row_ptr[idx + 1] = run; }
  }
  if (tid == 0) row_ptr[0] = 0;
}

__global__ __launch_bounds__(256) void scatter_edges(const int* __restrict__ ei,
                                                     const int* __restrict__ row_ptr,
                                                     int* __restrict__ cursor,
                                                     int* __restrict__ col) {
  int e = blockIdx.x * 256 + threadIdx.x;
  if (e >= E_TOT) return;
  int src, dst;
  if (e < N_EDGES) { src = ei[e]; dst = ei[N_EDGES + e]; }
  else             { src = e - N_EDGES; dst = src; }
  int pos = atomicAdd(&cursor[dst], 1);
  col[row_ptr[dst] + pos] = src;
}

// ---------------- combined fp32 -> fp16 cast: x, W1, W2 ----------------

#define CVT_N0 (N_NODES * 256 / 4)        /* 3,200,000 float4 for x  */
#define CVT_N1 (CVT_N0 + 512 * 256 / 4)   /* + 32768 for W1 */
#define CVT_N2 (CVT_N1 + 512 * 128 / 4)   /* + 16384 for W2 */

__global__ __launch_bounds__(256) void cvt_all_f16(
    const float* __restrict__ x,  __half* __restrict__ A16,
    const float* __restrict__ W1, __half* __restrict__ B1,
    const float* __restrict__ W2, __half* __restrict__ B2) {
  int i = blockIdx.x * 256 + threadIdx.x;
  const float* s; __half* d; int k;
  if (i < CVT_N0)      { s = x;  d = A16; k = i; }
  else if (i < CVT_N1) { s = W1; d = B1;  k = i - CVT_N0; }
  else if (i < CVT_N2) { s = W2; d = B2;  k = i - CVT_N1; }
  else return;
  float4 v = ((const float4*)s)[k];
  __half2 h01 = __float22half2_rn(make_float2(v.x, v.y));
  __half2 h23 = __float22half2_rn(make_float2(v.z, v.w));
  uint2 pk = make_uint2(*(u32*)&h01, *(u32*)&h23);
  ((uint2*)d)[k] = pk;
}

// ---------------- fp16 MFMA GEMM + fused attention epilogue ----------------
// C_fp16[MP,512] = A_fp16[M,K] @ B_fp16[512,K]^T, fp32 accumulate.
// Grid (MP/128, 4): block = 128 rows x 128 cols; col-block == head hb.
// Staging: global_load_lds width=16, 16 KB LDS (A,B planes), 2 barriers/K-step.
// Epilogue: per-row <xh,att_s/d> from fp32 accs via 16-lane shfl + LDS combine
// across the two col-waves (replaces node_att); scalar fp16 C stores (r3-style).

#define GLD16(gp, lp)                                                          \
  __builtin_amdgcn_global_load_lds(                                            \
      (const __attribute__((address_space(1))) u32*)(gp),                      \
      (__attribute__((address_space(3))) u32*)(lp), 16, 0, 0)

template <int K>
__global__ __launch_bounds__(256) void gemm_att(
    const __half* __restrict__ A, const __half* __restrict__ B,
    const float* __restrict__ att_s, const float* __restrict__ att_d,
    __half* __restrict__ C, float* __restrict__ as_, float* __restrict__ ad_) {
  __shared__ u16 sA[128 * 32];    // 8 KB plane, row*32 + k
  __shared__ u16 sB[128 * 32];
  __shared__ float sAtt[2][4][64];
  const int tid  = threadIdx.x;
  const int lane = tid & 63;
  const int wave = tid >> 6;
  const int m0 = blockIdx.x * 128;
  const int hb = blockIdx.y;
  const int n0 = hb * 128;
  const int wm = (wave >> 1) * 64, wn = (wave & 1) * 64;
  const int t = lane & 15, quad = lane >> 4, kq = quad * 8;

  f32x4 acc[4][4];
#pragma unroll
  for (int i = 0; i < 4; i++)
#pragma unroll
    for (int j = 0; j < 4; j++) acc[i][j] = (f32x4){0.f, 0.f, 0.f, 0.f};

  const int srow = tid >> 2;            // staging row (0..63), 2 r-iters
  const int skc  = (tid & 3) * 8;       // staging k offset (elements)

  for (int k0 = 0; k0 < K; k0 += 32) {
    __syncthreads();
#pragma unroll
    for (int r = 0; r < 2; ++r) {
      int row = r * 64 + srow;
      size_t aoff = (size_t)(m0 + row) * K + k0 + skc;
      size_t boff = (size_t)(n0 + row) * K + k0 + skc;
      int ld = r * 4096 + tid * 16;     // byte offset within the 8 KB plane
      GLD16(A + aoff, (char*)sA + ld);
      GLD16(B + boff, (char*)sB + ld);
    }
    __syncthreads();

    f16x8 a[4], b[4];
#pragma unroll
    for (int i = 0; i < 4; ++i) {
      a[i] = *(const f16x8*)&sA[(wm + t + i * 16) * 32 + kq];
      b[i] = *(const f16x8*)&sB[(wn + t + i * 16) * 32 + kq];
    }
#pragma unroll
    for (int i = 0; i < 4; ++i)
#pragma unroll
      for (int j = 0; j < 4; ++j)
        acc[i][j] = __builtin_amdgcn_mfma_f32_16x16x32_f16(a[i], b[j], acc[i][j], 0, 0, 0);
  }

  // ---- att partials: per-row dot with att vectors, from fp32 accs ----
  const float* asv = att_s + hb * CH;
  const float* adv = att_d + hb * CH;
#pragma unroll
  for (int i = 0; i < 4; ++i) {
    float sa[4] = {0.f, 0.f, 0.f, 0.f}, sd[4] = {0.f, 0.f, 0.f, 0.f};
#pragma unroll
    for (int j = 0; j < 4; ++j) {
      int c = wn + j * 16 + t;
      float sc = asv[c], dc = adv[c];
#pragma unroll
      for (int r = 0; r < 4; ++r) {
        sa[r] = fmaf(acc[i][j][r], sc, sa[r]);
        sd[r] = fmaf(acc[i][j][r], dc, sd[r]);
      }
    }
#pragma unroll
    for (int r = 0; r < 4; ++r) {
#pragma unroll
      for (int mask = 1; mask < 16; mask <<= 1) {
        sa[r] += __shfl_xor(sa[r], mask, 64);
        sd[r] += __shfl_xor(sd[r], mask, 64);
      }
      if (t == 0) {
        sAtt[0][wave][i * 16 + quad * 4 + r] = sa[r];
        sAtt[1][wave][i * 16 + quad * 4 + r] = sd[r];
      }
    }
  }

  // ---- C stores (scalar fp16, r3-style; C/D layout col=lane&15, row=quad*4+reg) ----
#pragma unroll
  for (int i = 0; i < 4; ++i)
#pragma unroll
    for (int j = 0; j < 4; ++j)
#pragma unroll
      for (int r = 0; r < 4; ++r) {
        int m = m0 + wm + i * 16 + quad * 4 + r;
        int n = n0 + wn + j * 16 + t;
        C[(size_t)m * NOUT + n] = __float2half(acc[i][j][r]);
      }

  __syncthreads();   // sAtt complete
  // ---- att finals: combine the two col-waves of each row-half ----
  if ((wave & 1) == 0) {
    int gm = m0 + (wave >> 1) * 64 + lane;
    if (gm < N_NODES) {
      as_[gm * HEADS + hb] = sAtt[0][wave][lane] + sAtt[0][wave + 1][lane];
      ad_[gm * HEADS + hb] = sAtt[1][wave][lane] + sAtt[1][wave + 1][lane];
    }
  }
}

// ---------------- GAT aggregation, fp16 gather ----------------
// one wave per dst node. lane -> (h, 8 channels) => one 16 B load per edge.
// No explicit segment-max (|alpha|max ~ 8 << 88, algebraically identical).
// HALF_OUT=1: fp16 out (feeds layer-2 GEMM directly). HALF_OUT=0: fp32 out.

template <bool HALF_OUT>
__global__ __launch_bounds__(256) void gat_aggregate_f16(const __half* __restrict__ xh,
                                                         const float* __restrict__ as_,
                                                         const float* __restrict__ ad_,
                                                         const int* __restrict__ row_ptr,
                                                         const int* __restrict__ col,
                                                         const float* __restrict__ bias,
                                                         void* __restrict__ outv) {
  int node = (blockIdx.x * 256 + threadIdx.x) >> 6;
  if (node >= N_NODES) return;
  int lane = threadIdx.x & 63;
  int h = lane >> 4, ls = lane & 15, cb = ls * 8;
  int s = row_ptr[node], e = row_ptr[node + 1];
  float adh = ad_[node * HEADS + h];

  float acc[8];
#pragma unroll
  for (int j = 0; j < 8; j++) acc[j] = 0.f;
  float denom = 0.f;

  auto accum = [&](uint4 q, float w) {
    __half2 q0 = *(__half2*)&q.x, q1 = *(__half2*)&q.y;
    __half2 q2 = *(__half2*)&q.z, q3 = *(__half2*)&q.w;
    float2 f0 = __half22float2(q0), f1 = __half22float2(q1);
    float2 f2 = __half22float2(q2), f3 = __half22float2(q3);
    acc[0] = fmaf(w, f0.x, acc[0]); acc[1] = fmaf(w, f0.y, acc[1]);
    acc[2] = fmaf(w, f1.x, acc[2]); acc[3] = fmaf(w, f1.y, acc[3]);
    acc[4] = fmaf(w, f2.x, acc[4]); acc[5] = fmaf(w, f2.y, acc[5]);
    acc[6] = fmaf(w, f3.x, acc[6]); acc[7] = fmaf(w, f3.y, acc[7]);
  };

  int i = s;
  for (; i + 4 <= e; i += 4) {
    int s0 = col[i], s1 = col[i + 1], s2 = col[i + 2], s3 = col[i + 3];
    float l0 = as_[s0 * HEADS + h];
    float l1 = as_[s1 * HEADS + h];
    float l2 = as_[s2 * HEADS + h];
    float l3 = as_[s3 * HEADS + h];
    uint4 q0 = *(const uint4*)(xh + (size_t)s0 * NOUT + h * CH + cb);
    uint4 q1 = *(const uint4*)(xh + (size_t)s1 * NOUT + h * CH + cb);
    uint4 q2 = *(const uint4*)(xh + (size_t)s2 * NOUT + h * CH + cb);
    uint4 q3 = *(const uint4*)(xh + (size_t)s3 * NOUT + h * CH + cb);
    float a0 = l0 + adh; a0 = (a0 >= 0.f) ? a0 : NEG_SLOPE * a0;
    float a1 = l1 + adh; a1 = (a1 >= 0.f) ? a1 : NEG_SLOPE * a1;
    float a2 = l2 + adh; a2 = (a2 >= 0.f) ? a2 : NEG_SLOPE * a2;
    float a3 = l3 + adh; a3 = (a3 >= 0.f) ? a3 : NEG_SLOPE * a3;
    float w0 = __expf(a0), w1 = __expf(a1), w2 = __expf(a2), w3 = __expf(a3);
    denom += (w0 + w1) + (w2 + w3);
    accum(q0, w0); accum(q1, w1); accum(q2, w2); accum(q3, w3);
  }
  for (; i < e; ++i) {
    int src = col[i];
    float l = as_[src * HEADS + h];
    uint4 q = *(const uint4*)(xh + (size_t)src * NOUT + h * CH + cb);
    float a = l + adh; a = (a >= 0.f) ? a : NEG_SLOPE * a;
    float w = __expf(a);
    denom += w;
    accum(q, w);
  }

  float inv = 1.f / (denom + 1e-16f);
#pragma unroll
  for (int j = 0; j < 8; j++) acc[j] *= inv;

  // mean over heads: butterfly over lane bits 4,5
#pragma unroll
  for (int j = 0; j < 8; j++) {
    acc[j] += __shfl_xor(acc[j], 16, 64);
    acc[j] += __shfl_xor(acc[j], 32, 64);
  }
  if (h == 0) {
    float r[8];
#pragma unroll
    for (int j = 0; j < 8; j++) r[j] = acc[j] * 0.25f + bias[cb + j];
    if (HALF_OUT) {
      __half2 o[4];
#pragma unroll
      for (int j = 0; j < 4; j++)
        o[j] = __float22half2_rn(make_float2(r[2 * j], r[2 * j + 1]));
      *(uint4*)((__half*)outv + (size_t)node * CH + cb) = *(uint4*)o;
    } else {
      float4 o0 = make_float4(r[0], r[1], r[2], r[3]);
      float4 o1 = make_float4(r[4], r[5], r[6], r[7]);
      *(float4*)((float*)outv + (size_t)node * CH + cb)     = o0;
      *(float4*)((float*)outv + (size_t)node * CH + cb + 4) = o1;
    }
  }
}

// ---------------- launch ----------------

extern "C" void kernel_launch(void* const* d_in, const int* in_sizes, int n_in,
                              void* d_out, int out_size, void* d_ws, size_t ws_size,
                              hipStream_t stream) {
  const float* x      = (const float*)d_in[0];
  const int*   ei     = (const int*)  d_in[1];
  const float* W1     = (const float*)d_in[2];
  const float* att_s1 = (const float*)d_in[3];
  const float* att_d1 = (const float*)d_in[4];
  const float* b1     = (const float*)d_in[5];
  const float* W2     = (const float*)d_in[6];
  const float* att_s2 = (const float*)d_in[7];
  const float* att_d2 = (const float*)d_in[8];
  const float* b2     = (const float*)d_in[9];
  float* out = (float*)d_out;

  char* ws = (char*)d_ws;
  size_t off = 0;
  auto alloc = [&](size_t bytes) -> void* {
    void* p = ws + off;
    off += (bytes + 255) & ~(size_t)255;
    return p;
  };
  __half* A1_16  = (__half*)alloc((size_t)MP * 256 * 2);   // 25.6 MB (x in fp16)
  __half* A2_16  = (__half*)alloc((size_t)MP * 128 * 2);   // 12.8 MB (layer-1 agg out)
  __half* B1_16  = (__half*)alloc((size_t)512 * 256 * 2);
  __half* B2_16  = (__half*)alloc((size_t)512 * 128 * 2);
  __half* xh16   = (__half*)alloc((size_t)MP * NOUT * 2);  // 51.2 MB
  float* as_     = (float*)alloc((size_t)N_NODES * HEADS * 4);
  float* ad_     = (float*)alloc((size_t)N_NODES * HEADS * 4);
  int*   row_ptr = (int*)alloc((size_t)(N_NODES + 1) * 4);
  int*   cursor  = (int*)alloc((size_t)N_NODES * 4);
  int*   col     = (int*)alloc((size_t)E_TOT * 4);

  const int edge_blocks = (E_TOT + 255) / 256;
  const int node_wave_blocks = (N_NODES + 3) / 4;
  dim3 ggrid(MP / 128, HEADS);   // 391 x 4

  // CSR build (by dst)
  hipMemsetAsync(cursor, 0, (size_t)N_NODES * 4, stream);
  count_deg<<<edge_blocks, 256, 0, stream>>>(ei, cursor);
  scan_deg_fast<<<1, 1024, 0, stream>>>(cursor, row_ptr);
  hipMemsetAsync(cursor, 0, (size_t)N_NODES * 4, stream);
  scatter_edges<<<edge_blocks, 256, 0, stream>>>(ei, row_ptr, cursor, col);

  // cast x, W1, W2 to fp16 in one pass
  cvt_all_f16<<<(CVT_N2 + 255) / 256, 256, 0, stream>>>(x, A1_16, W1, B1_16, W2, B2_16);

  // layer 1
  gemm_att<256><<<ggrid, 256, 0, stream>>>(A1_16, B1_16, att_s1, att_d1,
                                           xh16, as_, ad_);
  gat_aggregate_f16<true><<<node_wave_blocks, 256, 0, stream>>>(
      xh16, as_, ad_, row_ptr, col, b1, A2_16);

  // layer 2 (A = fp16 output of aggregate-1)
  gemm_att<128><<<ggrid, 256, 0, stream>>>(A2_16, B2_16, att_s2, att_d2,
                                           xh16, as_, ad_);
  gat_aggregate_f16<false><<<node_wave_blocks, 256, 0, stream>>>(
      xh16, as_, ad_, row_ptr, col, b2, out);
}